// Round 2
// baseline (2346.735 us; speedup 1.0000x reference)
//
#include <hip/hip_runtime.h>

#define N0c 100000
#define N1c 20000
#define Ec 320000
#define Tc 8
#define DINc 128
#define Hc 64
#define Cc 16

typedef __attribute__((ext_vector_type(8))) short short8;
typedef __attribute__((ext_vector_type(4))) float f32x4;
typedef uint uint_a __attribute__((may_alias));
typedef ushort ushort_a __attribute__((may_alias));
struct __align__(8) u2a { uint_a x, y; };

#define LOG2E 1.442695040888963f

__device__ __forceinline__ float sigm(float x) {
    return __builtin_amdgcn_rcpf(1.f + __builtin_amdgcn_exp2f(-LOG2E * x));
}
__device__ __forceinline__ float tanh_(float x) {
    return 2.f * __builtin_amdgcn_rcpf(1.f + __builtin_amdgcn_exp2f(-2.f * LOG2E * x)) - 1.f;
}
__device__ __forceinline__ ushort f2bf(float f) {
    uint u = __float_as_uint(f);
    uint r = u + 0x7FFF + ((u >> 16) & 1);
    return (ushort)(r >> 16);
}

// ---------------- bucketing ----------------
__global__ void hist_kernel(const int* __restrict__ elen, int* __restrict__ cnt) {
    __shared__ int h[8];
    if (threadIdx.x < 8) h[threadIdx.x] = 0;
    __syncthreads();
    int e = blockIdx.x * blockDim.x + threadIdx.x;
    if (e < Ec) atomicAdd(&h[elen[e] - 1], 1);
    __syncthreads();
    if (threadIdx.x < 8) atomicAdd(&cnt[threadIdx.x], h[threadIdx.x]);
}

__global__ void scan_kernel(int* __restrict__ cnt) {
    if (threadIdx.x == 0 && blockIdx.x == 0) {
        int s = 0;
        for (int i = 0; i < 8; ++i) { cnt[8 + i] = s; s += cnt[i]; }
    }
}

__global__ void scatter_kernel(const int* __restrict__ elen, int* __restrict__ cursor,
                               int* __restrict__ perm) {
    int e = blockIdx.x * blockDim.x + threadIdx.x;
    if (e < Ec) {
        int pos = atomicAdd(&cursor[elen[e] - 1], 1);
        perm[pos] = e;
    }
}

// ---------------- edge kernel: MFMA LSTM + MLP + scatter ----------------
// Wave handles 16 edges. Orientation: D[256 gate-rows x 16 edges].
// A = [Whh^T | Wih^T | bias | 0] as [256][96] bf16 in LDS.
// B per step = [h(64) | x(16)+bias1+pad] per edge.
__global__ __launch_bounds__(512, 2)
void edge_mfma_kernel(const float* __restrict__ nf,
                      const float* __restrict__ ef,
                      const float* __restrict__ st,
                      const float* __restrict__ pw,
                      const float* __restrict__ Wih,
                      const float* __restrict__ Whh,
                      const float* __restrict__ lb,
                      const float* __restrict__ eW,
                      const float* __restrict__ ebias,
                      const int* __restrict__ elen,
                      const int* __restrict__ src,
                      const int* __restrict__ dst,
                      const int* __restrict__ perm,
                      float* __restrict__ agg)
{
    __shared__ __align__(16) ushort sA[256 * 104];    // 53.2 KB  [gm][k<96 +pad]
    __shared__ __align__(16) ushort sEWT[64 * 200];   // 25.6 KB  [unit][k<192 +pad]
    __shared__ __align__(16) ushort sScr[8][3328];    // 53.2 KB  per-wave scratch
    __shared__ __align__(16) float sPW[128];

    const int tid = threadIdx.x;

    for (int idx = tid; idx < 64 * 256; idx += 512) {
        int kh = idx >> 8, gm = idx & 255;
        sA[gm * 104 + kh] = f2bf(Whh[idx]);
    }
    for (int idx = tid; idx < 16 * 256; idx += 512) {
        int kx = idx >> 8, gm = idx & 255;
        sA[gm * 104 + 64 + kx] = f2bf(Wih[idx]);
    }
    for (int idx = tid; idx < 256 * 16; idx += 512) {
        int gm = idx >> 4, k = idx & 15;
        sA[gm * 104 + 80 + k] = (k == 0) ? f2bf(lb[gm]) : (ushort)0;
    }
    for (int idx = tid; idx < 192 * 64; idx += 512) {
        int k = idx >> 6, u = idx & 63;
        sEWT[u * 200 + k] = f2bf(eW[idx]);
    }
    if (tid < 128) sPW[tid] = pw[tid];
    __syncthreads();

    const int lane = tid & 63;
    const int wv = tid >> 6;
    const int g = lane >> 4;      // k-group / row-group
    const int erow = lane & 15;   // edge within tile

    ushort_a* sXB = (ushort_a*)sScr[wv];           // [16 edges][136 us] (t*16+f)
    ushort_a* sHB = (ushort_a*)(sScr[wv] + 2176);  // [16 edges][72 us]  (unit)
    ushort_a* sCat = (ushort_a*)sScr[wv];          // [16 edges][200 us] overlay

    // epilogue bias (per-lane constants)
    f32x4 ebv[4];
    #pragma unroll
    for (int mt = 0; mt < 4; ++mt)
        #pragma unroll
        for (int r = 0; r < 4; ++r)
            ebv[mt][r] = ebias[mt * 16 + g * 4 + r];

    const int nTiles = Ec / 16;
    for (int tile = blockIdx.x * 8 + wv; tile < nTiles; tile += gridDim.x * 8) {
        int pe = 0, lenv = 0, dstv = 0, srcv = 0;
        if (lane < 16) {
            pe = perm[tile * 16 + lane];
            lenv = elen[pe];
            dstv = dst[pe];
            srcv = src[pe];
        }
        const int myLen = __shfl(lenv, erow);
        const int myDst = __shfl(dstv, erow);
        int tmax = myLen;
        tmax = max(tmax, __shfl_xor(tmax, 1));
        tmax = max(tmax, __shfl_xor(tmax, 2));
        tmax = max(tmax, __shfl_xor(tmax, 4));
        tmax = max(tmax, __shfl_xor(tmax, 8));

        // ---- stage x features (bf16) for t < len ----
        for (int i = lane; i < 16 * 120; i += 64) {
            int es = i / 120;
            int r = i - es * 120;
            int t = r / 15;
            int f = r - t * 15;
            int epe = __shfl(pe, es);
            int el = __shfl(lenv, es);
            if (t < el) sXB[es * 136 + t * 16 + f] = f2bf(ef[(size_t)epe * 120 + r]);
        }
        for (int i = lane; i < 16 * 8; i += 64) {
            int es = i >> 3, t = i & 7;
            int epe = __shfl(pe, es);
            int el = __shfl(lenv, es);
            if (t < el) sXB[es * 136 + t * 16 + 15] = f2bf(st[(size_t)epe * 8 + t]);
        }

        // ---- LSTM ----
        f32x4 h[4], c[4];
        #pragma unroll
        for (int m = 0; m < 4; ++m) {
            h[m] = (f32x4){0.f, 0.f, 0.f, 0.f};
            c[m] = (f32x4){0.f, 0.f, 0.f, 0.f};
        }

        for (int t = 0; t < tmax; ++t) {
            short8 bx;
            if (g < 2) {
                bx = *(const short8*)(sXB + erow * 136 + t * 16 + g * 8);
            } else {
                short8 z = {0, 0, 0, 0, 0, 0, 0, 0};
                if (g == 2) z[0] = (short)0x3F80;  // bf16 1.0 -> bias column k=80
                bx = z;
            }
            short8 bh0, bh1;
            if (t > 0) {
                bh0 = *(const short8*)(sHB + erow * 72 + g * 8);
                bh1 = *(const short8*)(sHB + erow * 72 + 32 + g * 8);
            }

            f32x4 acc[16];
            #pragma unroll
            for (int m = 0; m < 16; ++m) acc[m] = (f32x4){0.f, 0.f, 0.f, 0.f};

            #pragma unroll
            for (int m = 0; m < 16; ++m) {
                const ushort_a* arow = (const ushort_a*)sA + (m * 16 + erow) * 104;
                short8 a2 = *(const short8*)(arow + 64 + g * 8);  // k-tile2: x+bias
                acc[m] = __builtin_amdgcn_mfma_f32_16x16x32_bf16(a2, bx, acc[m], 0, 0, 0);
            }
            if (t > 0) {
                #pragma unroll
                for (int m = 0; m < 16; ++m) {
                    const ushort_a* arow = (const ushort_a*)sA + (m * 16 + erow) * 104;
                    short8 a0 = *(const short8*)(arow + g * 8);        // h 0..31
                    short8 a1 = *(const short8*)(arow + 32 + g * 8);   // h 32..63
                    acc[m] = __builtin_amdgcn_mfma_f32_16x16x32_bf16(a0, bh0, acc[m], 0, 0, 0);
                    acc[m] = __builtin_amdgcn_mfma_f32_16x16x32_bf16(a1, bh1, acc[m], 0, 0, 0);
                }
            }

            const bool valid = (t < myLen);
            #pragma unroll
            for (int m = 0; m < 4; ++m) {
                #pragma unroll
                for (int r = 0; r < 4; ++r) {
                    float ig = sigm(acc[m][r]);
                    float fg = sigm(acc[m + 4][r]);
                    float gg = tanh_(acc[m + 8][r]);
                    float og = sigm(acc[m + 12][r]);
                    float cn = fg * c[m][r] + ig * gg;
                    float hn = og * tanh_(cn);
                    if (valid) { c[m][r] = cn; h[m][r] = hn; }
                }
            }
            if (t + 1 < tmax) {
                #pragma unroll
                for (int m = 0; m < 4; ++m) {
                    u2a v;
                    v.x = (uint)f2bf(h[m][0]) | ((uint)f2bf(h[m][1]) << 16);
                    v.y = (uint)f2bf(h[m][2]) | ((uint)f2bf(h[m][3]) << 16);
                    *(u2a*)(sHB + erow * 72 + m * 16 + g * 4) = v;
                }
            }
        }

        // ---- h_src gather + rank-1 removal -> sCat[0..127] ----
        {
            const int e4 = lane >> 2, q = lane & 3;
            const int srcE = __shfl(srcv, e4);
            const float* hsrow = nf + (size_t)srcE * 128;
            float4 xs[8];
            float part = 0.f;
            #pragma unroll
            for (int i = 0; i < 8; ++i) {
                int c4 = q * 8 + i;
                xs[i] = *(const float4*)(hsrow + c4 * 4);
                float4 pv = *(const float4*)(sPW + c4 * 4);
                part += xs[i].x * pv.x + xs[i].y * pv.y + xs[i].z * pv.z + xs[i].w * pv.w;
            }
            part += __shfl_xor(part, 1);
            part += __shfl_xor(part, 2);
            #pragma unroll
            for (int i = 0; i < 8; ++i) {
                int c4 = q * 8 + i;
                float4 pv = *(const float4*)(sPW + c4 * 4);
                float hx = xs[i].x - part * pv.x;
                float hy = xs[i].y - part * pv.y;
                float hz = xs[i].z - part * pv.z;
                float hw = xs[i].w - part * pv.w;
                u2a v;
                v.x = (uint)f2bf(hx) | ((uint)f2bf(hy) << 16);
                v.y = (uint)f2bf(hz) | ((uint)f2bf(hw) << 16);
                *(u2a*)(sCat + e4 * 200 + c4 * 4) = v;
            }
        }
        // e_enc -> sCat[128..191]
        #pragma unroll
        for (int m = 0; m < 4; ++m) {
            u2a v;
            v.x = (uint)f2bf(h[m][0]) | ((uint)f2bf(h[m][1]) << 16);
            v.y = (uint)f2bf(h[m][2]) | ((uint)f2bf(h[m][3]) << 16);
            *(u2a*)(sCat + erow * 200 + 128 + m * 16 + g * 4) = v;
        }

        // ---- edge MLP: m = relu(cat @ eW + eb), D[64 units x 16 edges] ----
        f32x4 macc[4];
        #pragma unroll
        for (int mt = 0; mt < 4; ++mt) macc[mt] = (f32x4){0.f, 0.f, 0.f, 0.f};
        #pragma unroll
        for (int kt = 0; kt < 6; ++kt) {
            short8 bfrag = *(const short8*)(sCat + erow * 200 + kt * 32 + g * 8);
            #pragma unroll
            for (int mt = 0; mt < 4; ++mt) {
                short8 afrag = *(const short8*)((const ushort_a*)sEWT + (mt * 16 + erow) * 200 + kt * 32 + g * 8);
                macc[mt] = __builtin_amdgcn_mfma_f32_16x16x32_bf16(afrag, bfrag, macc[mt], 0, 0, 0);
            }
        }

        #pragma unroll
        for (int mt = 0; mt < 4; ++mt)
            #pragma unroll
            for (int r = 0; r < 4; ++r) {
                float v = fmaxf(macc[mt][r] + ebv[mt][r], 0.f);
                atomicAdd(&agg[(size_t)myDst * 64 + mt * 16 + g * 4 + r], v);
            }
    }
}

// ---------------- Node kernel (unchanged from round 1) ----------------
#define NB_WAVES 8
#define NB_THREADS (NB_WAVES * 64)
__global__ __launch_bounds__(NB_THREADS, 1)
void node_kernel(const float* __restrict__ nf,
                 const float* __restrict__ sgn,
                 const float* __restrict__ eW,
                 const float* __restrict__ ebias,
                 const float* __restrict__ nW,
                 const float* __restrict__ nbias,
                 const float* __restrict__ fcW,
                 const float* __restrict__ fcb,
                 const int* __restrict__ lnid,
                 const float* __restrict__ agg,
                 float* __restrict__ out,
                 int nWavesTotal)
{
    __shared__ float sEW[128 * 64];
    __shared__ float sNW[192 * 64];
    __shared__ float sFC[64 * 16];
    __shared__ float sCat[NB_WAVES][192];
    __shared__ float sAct[NB_WAVES][64];

    const int tid = threadIdx.x;
    for (int idx = tid; idx < 128 * 64; idx += NB_THREADS) sEW[idx] = eW[idx];
    for (int idx = tid; idx < 192 * 64; idx += NB_THREADS) sNW[idx] = nW[idx];
    for (int idx = tid; idx < 64 * 16; idx += NB_THREADS) sFC[idx] = fcW[idx];
    __syncthreads();

    const int lane = tid & 63;
    const int wv = tid >> 6;
    const int gwave = blockIdx.x * NB_WAVES + wv;

    const float ebv = ebias[lane];
    const float nbv = nbias[lane];
    const float fcbv = (lane < 16) ? fcb[lane] : 0.f;

    for (int n = gwave; n < N1c; n += nWavesTotal) {
        const int nid = lnid[n];
        float sh0 = nf[(size_t)nid * 128 + lane];
        float sh1 = nf[(size_t)nid * 128 + 64 + lane];
        sCat[wv][lane] = sh0;
        sCat[wv][64 + lane] = sh1;

        float tmp = ebv;
        #pragma unroll 8
        for (int cc = 0; cc < 128; ++cc) tmp += sCat[wv][cc] * sEW[cc * 64 + lane];
        float hu = (agg[(size_t)n * 64 + lane] - tmp) * sgn[n];
        sCat[wv][128 + lane] = hu;

        float acc = nbv;
        #pragma unroll 8
        for (int cc = 0; cc < 192; ++cc) acc += sCat[wv][cc] * sNW[cc * 64 + lane];
        acc = fmaxf(acc, 0.f);
        sAct[wv][lane] = acc;

        if (lane < 16) {
            float o = fcbv;
            #pragma unroll
            for (int j = 0; j < 64; ++j) o += sAct[wv][j] * sFC[j * 16 + lane];
            out[(size_t)n * 16 + lane] = o;
        }
    }
}

extern "C" void kernel_launch(void* const* d_in, const int* in_sizes, int n_in,
                              void* d_out, int out_size, void* d_ws, size_t ws_size,
                              hipStream_t stream) {
    const float* nf  = (const float*)d_in[0];
    const float* ef  = (const float*)d_in[1];
    const float* st  = (const float*)d_in[2];
    const float* sgn = (const float*)d_in[3];
    const float* pw  = (const float*)d_in[4];
    const float* Wih = (const float*)d_in[5];
    const float* Whh = (const float*)d_in[6];
    const float* lb  = (const float*)d_in[7];
    const float* eW  = (const float*)d_in[8];
    const float* eb  = (const float*)d_in[9];
    const float* nW  = (const float*)d_in[10];
    const float* nb  = (const float*)d_in[11];
    const float* fcW = (const float*)d_in[12];
    const float* fcb = (const float*)d_in[13];
    const int* elen = (const int*)d_in[14];
    const int* src  = (const int*)d_in[15];
    const int* dst  = (const int*)d_in[16];
    const int* lnid = (const int*)d_in[17];

    float* out = (float*)d_out;
    float* agg = (float*)d_ws;                               // 5,120,000 B
    int* cnt  = (int*)((char*)d_ws + 5120000);               // 16 ints
    int* perm = (int*)((char*)d_ws + 5120064);               // E ints

    hipMemsetAsync(d_ws, 0, 5120064, stream);

    hist_kernel<<<Ec / 256, 256, 0, stream>>>(elen, cnt);
    scan_kernel<<<1, 64, 0, stream>>>(cnt);
    scatter_kernel<<<Ec / 256, 256, 0, stream>>>(elen, cnt + 8, perm);

    edge_mfma_kernel<<<256, 512, 0, stream>>>(
        nf, ef, st, pw, Wih, Whh, lb, eW, eb, elen, src, dst, perm, agg);

    node_kernel<<<512, NB_THREADS, 0, stream>>>(
        nf, sgn, eW, eb, nW, nb, fcW, fcb, lnid, agg, out, 512 * NB_WAVES);
}

// Round 3
// 1144.132 us; speedup vs baseline: 2.0511x; 2.0511x over previous
//
#include <hip/hip_runtime.h>

#define N0c 100000
#define N1c 20000
#define Ec 320000
#define Tc 8
#define DINc 128
#define Hc 64
#define Cc 16

#define NBLK ((Ec + 1023) / 1024)   // 313 blocks for bucketing

typedef __attribute__((ext_vector_type(8))) short short8;
typedef __attribute__((ext_vector_type(4))) float f32x4;
typedef uint uint_a __attribute__((may_alias));
typedef ushort ushort_a __attribute__((may_alias));
struct __align__(8) u2a { uint_a x, y; };

#define LOG2E 1.442695040888963f

__device__ __forceinline__ float sigm(float x) {
    return __builtin_amdgcn_rcpf(1.f + __builtin_amdgcn_exp2f(-LOG2E * x));
}
__device__ __forceinline__ float tanh_(float x) {
    return 2.f * __builtin_amdgcn_rcpf(1.f + __builtin_amdgcn_exp2f(-2.f * LOG2E * x)) - 1.f;
}
__device__ __forceinline__ ushort f2bf(float f) {
    uint u = __float_as_uint(f);
    uint r = u + 0x7FFF + ((u >> 16) & 1);
    return (ushort)(r >> 16);
}

// ---------------- bucketing: deterministic counting sort by length ----------
__global__ void count_kernel(const int* __restrict__ elen, int* __restrict__ bc) {
    __shared__ int h[8];
    if (threadIdx.x < 8) h[threadIdx.x] = 0;
    __syncthreads();
    const int base = blockIdx.x * 1024;
    for (int i = threadIdx.x; i < 1024; i += 256) {
        int e = base + i;
        if (e < Ec) atomicAdd(&h[elen[e] - 1], 1);
    }
    __syncthreads();
    if (threadIdx.x < 8) bc[blockIdx.x * 8 + threadIdx.x] = h[threadIdx.x];
}

__global__ void offs_kernel(const int* __restrict__ bc, int* __restrict__ bo) {
    __shared__ int s[NBLK * 8];
    __shared__ int base[8];
    const int tid = threadIdx.x;
    for (int i = tid; i < NBLK * 8; i += 256) s[i] = bc[i];
    __syncthreads();
    if (tid == 0) {
        int tot[8];
        for (int b = 0; b < 8; ++b) {
            int t = 0;
            for (int blk = 0; blk < NBLK; ++blk) t += s[blk * 8 + b];
            tot[b] = t;
        }
        int run = 0;
        for (int b = 0; b < 8; ++b) { base[b] = run; run += tot[b]; }
    }
    __syncthreads();
    if (tid < 8) {
        int run = base[tid];
        for (int blk = 0; blk < NBLK; ++blk) {
            int t = s[blk * 8 + tid];
            s[blk * 8 + tid] = run;
            run += t;
        }
    }
    __syncthreads();
    for (int i = tid; i < NBLK * 8; i += 256) bo[i] = s[i];
}

__global__ void scatter2_kernel(const int* __restrict__ elen, const int* __restrict__ bo,
                                int* __restrict__ perm) {
    __shared__ int cnt[256][9];
    const int tid = threadIdx.x;
    const int base = blockIdx.x * 1024 + tid * 4;
    int lens[4];
    int lc0 = 0, lc1 = 0, lc2 = 0, lc3 = 0, lc4 = 0, lc5 = 0, lc6 = 0, lc7 = 0;
    #pragma unroll
    for (int j = 0; j < 4; ++j) {
        int e = base + j;
        int l = (e < Ec) ? elen[e] - 1 : -1;
        lens[j] = l;
        lc0 += (l == 0); lc1 += (l == 1); lc2 += (l == 2); lc3 += (l == 3);
        lc4 += (l == 4); lc5 += (l == 5); lc6 += (l == 6); lc7 += (l == 7);
    }
    cnt[tid][0] = lc0; cnt[tid][1] = lc1; cnt[tid][2] = lc2; cnt[tid][3] = lc3;
    cnt[tid][4] = lc4; cnt[tid][5] = lc5; cnt[tid][6] = lc6; cnt[tid][7] = lc7;
    __syncthreads();
    if (tid < 8) {
        int run = bo[blockIdx.x * 8 + tid];
        for (int i = 0; i < 256; ++i) {
            int t = cnt[i][tid];
            cnt[i][tid] = run;
            run += t;
        }
    }
    __syncthreads();
    #pragma unroll
    for (int b = 0; b < 8; ++b) {
        int p = cnt[tid][b];
        #pragma unroll
        for (int j = 0; j < 4; ++j) {
            if (lens[j] == b) perm[p++] = base + j;
        }
    }
}

// ---------------- edge kernel: MFMA LSTM + MLP + scatter ----------------
// Wave handles 16 edges. Orientation: D[256 gate-rows x 16 edges].
// A = [Whh^T | Wih^T | bias | 0] as [256][96] bf16 in LDS.
// B per step = [h(64) | x(16)+bias1+pad] per edge.
__global__ __launch_bounds__(512, 2)
void edge_mfma_kernel(const float* __restrict__ nf,
                      const float* __restrict__ ef,
                      const float* __restrict__ st,
                      const float* __restrict__ pw,
                      const float* __restrict__ Wih,
                      const float* __restrict__ Whh,
                      const float* __restrict__ lb,
                      const float* __restrict__ eW,
                      const float* __restrict__ ebias,
                      const int* __restrict__ elen,
                      const int* __restrict__ src,
                      const int* __restrict__ dst,
                      const int* __restrict__ perm,
                      float* __restrict__ agg)
{
    __shared__ __align__(16) ushort sA[256 * 104];    // 53.2 KB  [gm][k<96 +pad]
    __shared__ __align__(16) ushort sEWT[64 * 200];   // 25.6 KB  [unit][k<192 +pad]
    __shared__ __align__(16) ushort sScr[8][3328];    // 53.2 KB  per-wave scratch
    __shared__ __align__(16) float sPW[128];

    const int tid = threadIdx.x;

    for (int idx = tid; idx < 64 * 256; idx += 512) {
        int kh = idx >> 8, gm = idx & 255;
        sA[gm * 104 + kh] = f2bf(Whh[idx]);
    }
    for (int idx = tid; idx < 16 * 256; idx += 512) {
        int kx = idx >> 8, gm = idx & 255;
        sA[gm * 104 + 64 + kx] = f2bf(Wih[idx]);
    }
    for (int idx = tid; idx < 256 * 16; idx += 512) {
        int gm = idx >> 4, k = idx & 15;
        sA[gm * 104 + 80 + k] = (k == 0) ? f2bf(lb[gm]) : (ushort)0;
    }
    for (int idx = tid; idx < 192 * 64; idx += 512) {
        int k = idx >> 6, u = idx & 63;
        sEWT[u * 200 + k] = f2bf(eW[idx]);
    }
    if (tid < 128) sPW[tid] = pw[tid];
    __syncthreads();

    const int lane = tid & 63;
    const int wv = tid >> 6;
    const int g = lane >> 4;      // k-group / row-group
    const int erow = lane & 15;   // edge within tile

    ushort_a* sXB = (ushort_a*)sScr[wv];           // [16 edges][136 us] (t*16+f)
    ushort_a* sHB = (ushort_a*)(sScr[wv] + 2176);  // [16 edges][72 us]  (unit)
    ushort_a* sCat = (ushort_a*)sScr[wv];          // [16 edges][200 us] overlay

    // epilogue bias (per-lane constants)
    f32x4 ebv[4];
    #pragma unroll
    for (int mt = 0; mt < 4; ++mt)
        #pragma unroll
        for (int r = 0; r < 4; ++r)
            ebv[mt][r] = ebias[mt * 16 + g * 4 + r];

    const int nTiles = Ec / 16;
    for (int tile = blockIdx.x * 8 + wv; tile < nTiles; tile += gridDim.x * 8) {
        int pe = 0, lenv = 0, dstv = 0, srcv = 0;
        if (lane < 16) {
            pe = perm[tile * 16 + lane];
            lenv = elen[pe];
            dstv = dst[pe];
            srcv = src[pe];
        }
        const int myLen = __shfl(lenv, erow);
        const int myDst = __shfl(dstv, erow);
        int tmax = myLen;
        tmax = max(tmax, __shfl_xor(tmax, 1));
        tmax = max(tmax, __shfl_xor(tmax, 2));
        tmax = max(tmax, __shfl_xor(tmax, 4));
        tmax = max(tmax, __shfl_xor(tmax, 8));

        // ---- stage x features (bf16) for t < len ----
        for (int i = lane; i < 16 * 120; i += 64) {
            int es = i / 120;
            int r = i - es * 120;
            int t = r / 15;
            int f = r - t * 15;
            int epe = __shfl(pe, es);
            int el = __shfl(lenv, es);
            if (t < el) sXB[es * 136 + t * 16 + f] = f2bf(ef[(size_t)epe * 120 + r]);
        }
        for (int i = lane; i < 16 * 8; i += 64) {
            int es = i >> 3, t = i & 7;
            int epe = __shfl(pe, es);
            int el = __shfl(lenv, es);
            if (t < el) sXB[es * 136 + t * 16 + 15] = f2bf(st[(size_t)epe * 8 + t]);
        }

        // ---- LSTM ----
        f32x4 h[4], c[4];
        #pragma unroll
        for (int m = 0; m < 4; ++m) {
            h[m] = (f32x4){0.f, 0.f, 0.f, 0.f};
            c[m] = (f32x4){0.f, 0.f, 0.f, 0.f};
        }

        for (int t = 0; t < tmax; ++t) {
            short8 bx;
            if (g < 2) {
                bx = *(const short8*)(sXB + erow * 136 + t * 16 + g * 8);
            } else {
                short8 z = {0, 0, 0, 0, 0, 0, 0, 0};
                if (g == 2) z[0] = (short)0x3F80;  // bf16 1.0 -> bias column k=80
                bx = z;
            }
            short8 bh0, bh1;
            if (t > 0) {
                bh0 = *(const short8*)(sHB + erow * 72 + g * 8);
                bh1 = *(const short8*)(sHB + erow * 72 + 32 + g * 8);
            }

            f32x4 acc[16];
            #pragma unroll
            for (int m = 0; m < 16; ++m) acc[m] = (f32x4){0.f, 0.f, 0.f, 0.f};

            #pragma unroll
            for (int m = 0; m < 16; ++m) {
                const ushort_a* arow = (const ushort_a*)sA + (m * 16 + erow) * 104;
                short8 a2 = *(const short8*)(arow + 64 + g * 8);  // k-tile2: x+bias
                acc[m] = __builtin_amdgcn_mfma_f32_16x16x32_bf16(a2, bx, acc[m], 0, 0, 0);
            }
            if (t > 0) {
                #pragma unroll
                for (int m = 0; m < 16; ++m) {
                    const ushort_a* arow = (const ushort_a*)sA + (m * 16 + erow) * 104;
                    short8 a0 = *(const short8*)(arow + g * 8);        // h 0..31
                    short8 a1 = *(const short8*)(arow + 32 + g * 8);   // h 32..63
                    acc[m] = __builtin_amdgcn_mfma_f32_16x16x32_bf16(a0, bh0, acc[m], 0, 0, 0);
                    acc[m] = __builtin_amdgcn_mfma_f32_16x16x32_bf16(a1, bh1, acc[m], 0, 0, 0);
                }
            }

            const bool valid = (t < myLen);
            #pragma unroll
            for (int m = 0; m < 4; ++m) {
                #pragma unroll
                for (int r = 0; r < 4; ++r) {
                    float ig = sigm(acc[m][r]);
                    float fg = sigm(acc[m + 4][r]);
                    float gg = tanh_(acc[m + 8][r]);
                    float og = sigm(acc[m + 12][r]);
                    float cn = fg * c[m][r] + ig * gg;
                    float hn = og * tanh_(cn);
                    if (valid) { c[m][r] = cn; h[m][r] = hn; }
                }
            }
            if (t + 1 < tmax) {
                #pragma unroll
                for (int m = 0; m < 4; ++m) {
                    u2a v;
                    v.x = (uint)f2bf(h[m][0]) | ((uint)f2bf(h[m][1]) << 16);
                    v.y = (uint)f2bf(h[m][2]) | ((uint)f2bf(h[m][3]) << 16);
                    *(u2a*)(sHB + erow * 72 + m * 16 + g * 4) = v;
                }
            }
        }

        // ---- h_src gather + rank-1 removal -> sCat[0..127] ----
        {
            const int e4 = lane >> 2, q = lane & 3;
            const int srcE = __shfl(srcv, e4);
            const float* hsrow = nf + (size_t)srcE * 128;
            float4 xs[8];
            float part = 0.f;
            #pragma unroll
            for (int i = 0; i < 8; ++i) {
                int c4 = q * 8 + i;
                xs[i] = *(const float4*)(hsrow + c4 * 4);
                float4 pv = *(const float4*)(sPW + c4 * 4);
                part += xs[i].x * pv.x + xs[i].y * pv.y + xs[i].z * pv.z + xs[i].w * pv.w;
            }
            part += __shfl_xor(part, 1);
            part += __shfl_xor(part, 2);
            #pragma unroll
            for (int i = 0; i < 8; ++i) {
                int c4 = q * 8 + i;
                float4 pv = *(const float4*)(sPW + c4 * 4);
                float hx = xs[i].x - part * pv.x;
                float hy = xs[i].y - part * pv.y;
                float hz = xs[i].z - part * pv.z;
                float hw = xs[i].w - part * pv.w;
                u2a v;
                v.x = (uint)f2bf(hx) | ((uint)f2bf(hy) << 16);
                v.y = (uint)f2bf(hz) | ((uint)f2bf(hw) << 16);
                *(u2a*)(sCat + e4 * 200 + c4 * 4) = v;
            }
        }
        // e_enc -> sCat[128..191]
        #pragma unroll
        for (int m = 0; m < 4; ++m) {
            u2a v;
            v.x = (uint)f2bf(h[m][0]) | ((uint)f2bf(h[m][1]) << 16);
            v.y = (uint)f2bf(h[m][2]) | ((uint)f2bf(h[m][3]) << 16);
            *(u2a*)(sCat + erow * 200 + 128 + m * 16 + g * 4) = v;
        }

        // ---- edge MLP: m = relu(cat @ eW + eb), D[64 units x 16 edges] ----
        f32x4 macc[4];
        #pragma unroll
        for (int mt = 0; mt < 4; ++mt) macc[mt] = (f32x4){0.f, 0.f, 0.f, 0.f};
        #pragma unroll
        for (int kt = 0; kt < 6; ++kt) {
            short8 bfrag = *(const short8*)(sCat + erow * 200 + kt * 32 + g * 8);
            #pragma unroll
            for (int mt = 0; mt < 4; ++mt) {
                short8 afrag = *(const short8*)((const ushort_a*)sEWT + (mt * 16 + erow) * 200 + kt * 32 + g * 8);
                macc[mt] = __builtin_amdgcn_mfma_f32_16x16x32_bf16(afrag, bfrag, macc[mt], 0, 0, 0);
            }
        }

        #pragma unroll
        for (int mt = 0; mt < 4; ++mt)
            #pragma unroll
            for (int r = 0; r < 4; ++r) {
                float v = fmaxf(macc[mt][r] + ebv[mt][r], 0.f);
                atomicAdd(&agg[(size_t)myDst * 64 + mt * 16 + g * 4 + r], v);
            }
    }
}

// ---------------- Node kernel ----------------
#define NB_WAVES 8
#define NB_THREADS (NB_WAVES * 64)
__global__ __launch_bounds__(NB_THREADS, 1)
void node_kernel(const float* __restrict__ nf,
                 const float* __restrict__ sgn,
                 const float* __restrict__ eW,
                 const float* __restrict__ ebias,
                 const float* __restrict__ nW,
                 const float* __restrict__ nbias,
                 const float* __restrict__ fcW,
                 const float* __restrict__ fcb,
                 const int* __restrict__ lnid,
                 const float* __restrict__ agg,
                 float* __restrict__ out,
                 int nWavesTotal)
{
    __shared__ float sEW[128 * 64];
    __shared__ float sNW[192 * 64];
    __shared__ float sFC[64 * 16];
    __shared__ float sCat[NB_WAVES][192];
    __shared__ float sAct[NB_WAVES][64];

    const int tid = threadIdx.x;
    for (int idx = tid; idx < 128 * 64; idx += NB_THREADS) sEW[idx] = eW[idx];
    for (int idx = tid; idx < 192 * 64; idx += NB_THREADS) sNW[idx] = nW[idx];
    for (int idx = tid; idx < 64 * 16; idx += NB_THREADS) sFC[idx] = fcW[idx];
    __syncthreads();

    const int lane = tid & 63;
    const int wv = tid >> 6;
    const int gwave = blockIdx.x * NB_WAVES + wv;

    const float ebv = ebias[lane];
    const float nbv = nbias[lane];
    const float fcbv = (lane < 16) ? fcb[lane] : 0.f;

    for (int n = gwave; n < N1c; n += nWavesTotal) {
        const int nid = lnid[n];
        float sh0 = nf[(size_t)nid * 128 + lane];
        float sh1 = nf[(size_t)nid * 128 + 64 + lane];
        sCat[wv][lane] = sh0;
        sCat[wv][64 + lane] = sh1;

        float tmp = ebv;
        #pragma unroll 8
        for (int cc = 0; cc < 128; ++cc) tmp += sCat[wv][cc] * sEW[cc * 64 + lane];
        float hu = (agg[(size_t)n * 64 + lane] - tmp) * sgn[n];
        sCat[wv][128 + lane] = hu;

        float acc = nbv;
        #pragma unroll 8
        for (int cc = 0; cc < 192; ++cc) acc += sCat[wv][cc] * sNW[cc * 64 + lane];
        acc = fmaxf(acc, 0.f);
        sAct[wv][lane] = acc;

        if (lane < 16) {
            float o = fcbv;
            #pragma unroll
            for (int j = 0; j < 64; ++j) o += sAct[wv][j] * sFC[j * 16 + lane];
            out[(size_t)n * 16 + lane] = o;
        }
    }
}

extern "C" void kernel_launch(void* const* d_in, const int* in_sizes, int n_in,
                              void* d_out, int out_size, void* d_ws, size_t ws_size,
                              hipStream_t stream) {
    const float* nf  = (const float*)d_in[0];
    const float* ef  = (const float*)d_in[1];
    const float* st  = (const float*)d_in[2];
    const float* sgn = (const float*)d_in[3];
    const float* pw  = (const float*)d_in[4];
    const float* Wih = (const float*)d_in[5];
    const float* Whh = (const float*)d_in[6];
    const float* lb  = (const float*)d_in[7];
    const float* eW  = (const float*)d_in[8];
    const float* eb  = (const float*)d_in[9];
    const float* nW  = (const float*)d_in[10];
    const float* nb  = (const float*)d_in[11];
    const float* fcW = (const float*)d_in[12];
    const float* fcb = (const float*)d_in[13];
    const int* elen = (const int*)d_in[14];
    const int* src  = (const int*)d_in[15];
    const int* dst  = (const int*)d_in[16];
    const int* lnid = (const int*)d_in[17];

    float* out = (float*)d_out;
    float* agg = (float*)d_ws;                               // 5,120,000 B
    int* bc   = (int*)((char*)d_ws + 5120000);               // NBLK*8 ints
    int* bo   = (int*)((char*)d_ws + 5120000 + NBLK * 8 * 4);
    int* perm = (int*)((char*)d_ws + 5120000 + 2 * NBLK * 8 * 4 + 64);

    hipMemsetAsync(agg, 0, (size_t)N1c * 64 * sizeof(float), stream);

    count_kernel<<<NBLK, 256, 0, stream>>>(elen, bc);
    offs_kernel<<<1, 256, 0, stream>>>(bc, bo);
    scatter2_kernel<<<NBLK, 256, 0, stream>>>(elen, bo, perm);

    edge_mfma_kernel<<<256, 512, 0, stream>>>(
        nf, ef, st, pw, Wih, Whh, lb, eW, eb, elen, src, dst, perm, agg);

    node_kernel<<<512, NB_THREADS, 0, stream>>>(
        nf, sgn, eW, eb, nW, nb, fcW, fcb, lnid, agg, out, 512 * NB_WAVES);
}